// Round 1
// baseline (263.501 us; speedup 1.0000x reference)
//
#include <hip/hip_runtime.h>

// ws layout (float offsets)
#define OFF_VR  0      // 16x16 V real, row-major [row*16+col]
#define OFF_VI  256    // 16x16 V imag
#define OFF_H   512    // 16x4  H[l][j] = sum_q sign_q(l) * W_read[q][j]
#define OFF_W2  576    // 16    W_enc rows 512..515 flattened [j*4+q]
#define OFF_BR  592    // 4     b_read
#define OFF_PRE 640    // 65536*4 floats: pre[t*512+b][q] = x[b,t,:]@W_enc[:512] + b_enc

__device__ __forceinline__ float fast_tanh(float x) {
  // tanh(x) = 1 - 2/(exp(2x)+1); exp via v_exp_f32 (exp2), rcp via v_rcp_f32
  float e = __builtin_amdgcn_exp2f(x * 2.8853902f);          // 2*log2(e)
  return 1.0f - 2.0f * __builtin_amdgcn_rcpf(e + 1.0f);
}

// ---------------------------------------------------------------------------
// Setup: build V (16x16 complex circuit unitary), H, W2, br from theta/W on device
// ---------------------------------------------------------------------------
__global__ void setup_kernel(const float* __restrict__ theta,
                             const float* __restrict__ W_read,
                             const float* __restrict__ b_read,
                             const float* __restrict__ W_enc,
                             float* __restrict__ ws) {
  const int tid = threadIdx.x;
  if (tid >= 16) return;

  ws[OFF_W2 + tid] = W_enc[2048 + tid];            // rows 512..515 of (516,4)
  if (tid < 4) ws[OFF_BR + tid] = b_read[tid];

  {  // H[tid][j]
    float acc0 = 0.f, acc1 = 0.f, acc2 = 0.f, acc3 = 0.f;
    #pragma unroll
    for (int q = 0; q < 4; ++q) {
      float sgn = ((tid >> (3 - q)) & 1) ? -1.0f : 1.0f;   // wire q <-> bit (3-q)
      acc0 += sgn * W_read[q * 4 + 0];
      acc1 += sgn * W_read[q * 4 + 1];
      acc2 += sgn * W_read[q * 4 + 2];
      acc3 += sgn * W_read[q * 4 + 3];
    }
    ws[OFF_H + tid * 4 + 0] = acc0;
    ws[OFF_H + tid * 4 + 1] = acc1;
    ws[OFF_H + tid * 4 + 2] = acc2;
    ws[OFF_H + tid * 4 + 3] = acc3;
  }

  // Simulate basis column `tid` through the constant part of the circuit.
  float sr[16], si[16];
  #pragma unroll
  for (int i = 0; i < 16; ++i) { sr[i] = (i == tid) ? 1.f : 0.f; si[i] = 0.f; }

  #pragma unroll
  for (int l = 0; l < 2; ++l) {
    #pragma unroll
    for (int q = 0; q < 4; ++q) {
      const float a0 = 0.5f * theta[l * 12 + q * 3 + 0];   // RX angle/2
      const float a1 = 0.5f * theta[l * 12 + q * 3 + 1];   // RZ angle/2
      const float a2 = 0.5f * theta[l * 12 + q * 3 + 2];   // RY angle/2
      float cx = cosf(a0), sx = sinf(a0);
      float cz = cosf(a1), sz = sinf(a1);
      float cy = cosf(a2), sy = sinf(a2);
      // M = RZ @ RX
      float m00r =  cz * cx, m00i = -sz * cx;
      float m01r = -sz * sx, m01i = -cz * sx;
      float m10r =  sz * sx, m10i = -cz * sx;
      float m11r =  cz * cx, m11i =  sz * cx;
      // U = RY @ M   (RY real)
      float u00r = cy * m00r - sy * m10r, u00i = cy * m00i - sy * m10i;
      float u01r = cy * m01r - sy * m11r, u01i = cy * m01i - sy * m11i;
      float u10r = sy * m00r + cy * m10r, u10i = sy * m00i + cy * m10i;
      float u11r = sy * m01r + cy * m11r, u11i = sy * m01i + cy * m11i;
      const int m = 8 >> q;                                // wire q <-> bit (3-q)
      #pragma unroll
      for (int i = 0; i < 16; ++i) {
        if (i & m) continue;
        const int i1 = i | m;
        float ar = sr[i], ai = si[i], br2 = sr[i1], bi2 = si[i1];
        sr[i]  = u00r * ar - u00i * ai + u01r * br2 - u01i * bi2;
        si[i]  = u00r * ai + u00i * ar + u01r * bi2 + u01i * br2;
        sr[i1] = u10r * ar - u10i * ai + u11r * br2 - u11i * bi2;
        si[i1] = u10r * ai + u10i * ar + u11r * bi2 + u11i * br2;
      }
    }
    #pragma unroll
    for (int c = 0; c < 3; ++c) {                          // CNOT(c, c+1)
      const int mc = 8 >> c, mt = 8 >> (c + 1);
      #pragma unroll
      for (int i = 0; i < 16; ++i) {
        if ((i & mc) && !(i & mt)) {
          const int i1 = i | mt;
          float tr = sr[i]; sr[i] = sr[i1]; sr[i1] = tr;
          float ti = si[i]; si[i] = si[i1]; si[i1] = ti;
        }
      }
    }
  }
  #pragma unroll
  for (int i = 0; i < 16; ++i) {
    ws[OFF_VR + i * 16 + tid] = sr[i];   // row i, col tid
    ws[OFF_VI + i * 16 + tid] = si[i];
  }
}

// ---------------------------------------------------------------------------
// pre[t,b,:] = x[b,t,:] @ W_enc[:512,:] + b_enc      (memory-bound, 128 MB read)
// 16 lanes per row; lane j covers e = c*64 + j*4 + {0..3}, c = 0..7
// ---------------------------------------------------------------------------
__global__ __launch_bounds__(256, 2) void enc_gemm(const float* __restrict__ x,
                                                   const float* __restrict__ W_enc,
                                                   const float* __restrict__ b_enc,
                                                   float* __restrict__ ws) {
  const int j = threadIdx.x & 15;
  const int g = (blockIdx.x * 256 + threadIdx.x) >> 4;     // group id: 0..8191

  float4 W[8][4];
  #pragma unroll
  for (int c = 0; c < 8; ++c)
    #pragma unroll
    for (int k = 0; k < 4; ++k)
      W[c][k] = *(const float4*)&W_enc[(c * 64 + j * 4 + k) * 4];

  const float4 be = *(const float4*)b_enc;
  float* pre = ws + OFF_PRE;

  for (int r = g; r < 65536; r += 8192) {                  // row = b*128 + t
    const float* xr = x + (size_t)r * 512;
    float a0 = 0.f, a1 = 0.f, a2 = 0.f, a3 = 0.f;
    #pragma unroll
    for (int c = 0; c < 8; ++c) {
      float4 xv = *(const float4*)&xr[c * 64 + (j << 2)];
      a0 = fmaf(xv.x, W[c][0].x, a0); a0 = fmaf(xv.y, W[c][1].x, a0);
      a0 = fmaf(xv.z, W[c][2].x, a0); a0 = fmaf(xv.w, W[c][3].x, a0);
      a1 = fmaf(xv.x, W[c][0].y, a1); a1 = fmaf(xv.y, W[c][1].y, a1);
      a1 = fmaf(xv.z, W[c][2].y, a1); a1 = fmaf(xv.w, W[c][3].y, a1);
      a2 = fmaf(xv.x, W[c][0].z, a2); a2 = fmaf(xv.y, W[c][1].z, a2);
      a2 = fmaf(xv.z, W[c][2].z, a2); a2 = fmaf(xv.w, W[c][3].z, a2);
      a3 = fmaf(xv.x, W[c][0].w, a3); a3 = fmaf(xv.y, W[c][1].w, a3);
      a3 = fmaf(xv.z, W[c][2].w, a3); a3 = fmaf(xv.w, W[c][3].w, a3);
    }
    #pragma unroll
    for (int m = 1; m < 16; m <<= 1) {
      a0 += __shfl_xor(a0, m); a1 += __shfl_xor(a1, m);
      a2 += __shfl_xor(a2, m); a3 += __shfl_xor(a3, m);
    }
    if (j == 0) {
      const int t = r & 127, b = r >> 7;
      *(float4*)&pre[(size_t)(t * 512 + b) * 4] =
          make_float4(a0 + be.x, a1 + be.y, a2 + be.z, a3 + be.w);
    }
  }
}

// ---------------------------------------------------------------------------
// Recurrence: 16 lanes per sample; lane = one statevector index.
// Per step: ang = tanh(pre + h@W2); enc = product state; w = Vrow . enc;
// p = |w|^2; z_j = sum_lanes p*H[l][j] (butterfly); h = tanh(z + br).
// ---------------------------------------------------------------------------
__global__ __launch_bounds__(64) void recur_kernel(const float* __restrict__ ws,
                                                   float* __restrict__ out) {
  const int gtid = blockIdx.x * 64 + threadIdx.x;
  const int s  = gtid >> 4;               // sample 0..511
  const int sl = threadIdx.x & 15;        // statevector index

  float Vr[16], Vi[16];
  #pragma unroll
  for (int j = 0; j < 16; j += 4) {
    float4 v = *(const float4*)&ws[OFF_VR + sl * 16 + j];
    Vr[j] = v.x; Vr[j + 1] = v.y; Vr[j + 2] = v.z; Vr[j + 3] = v.w;
    float4 w = *(const float4*)&ws[OFF_VI + sl * 16 + j];
    Vi[j] = w.x; Vi[j + 1] = w.y; Vi[j + 2] = w.z; Vi[j + 3] = w.w;
  }
  const float4 Hv  = *(const float4*)&ws[OFF_H + sl * 4];
  const float4 brv = *(const float4*)&ws[OFF_BR];
  float W2[16];
  #pragma unroll
  for (int j = 0; j < 16; j += 4) {
    float4 v = *(const float4*)&ws[OFF_W2 + j];
    W2[j] = v.x; W2[j + 1] = v.y; W2[j + 2] = v.z; W2[j + 3] = v.w;
  }

  const float4* pre4 = (const float4*)(ws + OFF_PRE);
  float h0 = 0.f, h1 = 0.f, h2 = 0.f, h3 = 0.f;
  float4 pv = pre4[s];                    // t = 0

  for (int t = 0; t < 128; ++t) {
    const int tn = (t + 1 < 128) ? t + 1 : 127;
    float4 pvn = pre4[tn * 512 + s];      // prefetch next step

    // angles (as tanh values; ang = pi*tanh, we only need ang/2 in revolutions)
    float u0 = pv.x + h0 * W2[0]  + h1 * W2[4]  + h2 * W2[8]  + h3 * W2[12];
    float u1 = pv.y + h0 * W2[1]  + h1 * W2[5]  + h2 * W2[9]  + h3 * W2[13];
    float u2 = pv.z + h0 * W2[2]  + h1 * W2[6]  + h2 * W2[10] + h3 * W2[14];
    float u3 = pv.w + h0 * W2[3]  + h1 * W2[7]  + h2 * W2[11] + h3 * W2[15];
    float t0 = fast_tanh(u0), t1 = fast_tanh(u1), t2 = fast_tanh(u2), t3 = fast_tanh(u3);
    // sin/cos(ang/2) = sin/cos(2*pi * tanh/4): HW sin/cos take revolutions
    float r0 = t0 * 0.25f, r1 = t1 * 0.25f, r2 = t2 * 0.25f, r3 = t3 * 0.25f;
    float c0 = __builtin_amdgcn_cosf(r0), s0 = __builtin_amdgcn_sinf(r0);
    float c1 = __builtin_amdgcn_cosf(r1), s1 = __builtin_amdgcn_sinf(r1);
    float c2 = __builtin_amdgcn_cosf(r2), s2 = __builtin_amdgcn_sinf(r2);
    float c3 = __builtin_amdgcn_cosf(r3), s3 = __builtin_amdgcn_sinf(r3);

    // product-state tree: enc[j], j = w0*8 + w1*4 + w2*2 + w3
    float e00 = c0 * c1, e01 = c0 * s1, e10 = s0 * c1, e11 = s0 * s1;
    float f0 = e00 * c2, f1 = e00 * s2, f2 = e01 * c2, f3 = e01 * s2;
    float f4 = e10 * c2, f5 = e10 * s2, f6 = e11 * c2, f7 = e11 * s2;
    float enc[16];
    enc[0]  = f0 * c3; enc[1]  = f0 * s3; enc[2]  = f1 * c3; enc[3]  = f1 * s3;
    enc[4]  = f2 * c3; enc[5]  = f2 * s3; enc[6]  = f3 * c3; enc[7]  = f3 * s3;
    enc[8]  = f4 * c3; enc[9]  = f4 * s3; enc[10] = f5 * c3; enc[11] = f5 * s3;
    enc[12] = f6 * c3; enc[13] = f6 * s3; enc[14] = f7 * c3; enc[15] = f7 * s3;

    // this lane's final amplitude: row sl of V times enc (enc real)
    float wrA = 0.f, wrB = 0.f, wiA = 0.f, wiB = 0.f;
    #pragma unroll
    for (int j = 0; j < 8; ++j)  { wrA = fmaf(Vr[j], enc[j], wrA); wiA = fmaf(Vi[j], enc[j], wiA); }
    #pragma unroll
    for (int j = 8; j < 16; ++j) { wrB = fmaf(Vr[j], enc[j], wrB); wiB = fmaf(Vi[j], enc[j], wiB); }
    float wr = wrA + wrB, wi = wiA + wiB;
    float p  = wr * wr + wi * wi;

    // z_j = sum over 16 lanes of p * H[l][j]  (butterfly leaves sum in all lanes)
    float z0 = p * Hv.x, z1 = p * Hv.y, z2 = p * Hv.z, z3 = p * Hv.w;
    #pragma unroll
    for (int m = 1; m < 16; m <<= 1) {
      z0 += __shfl_xor(z0, m); z1 += __shfl_xor(z1, m);
      z2 += __shfl_xor(z2, m); z3 += __shfl_xor(z3, m);
    }
    h0 = fast_tanh(z0 + brv.x);
    h1 = fast_tanh(z1 + brv.y);
    h2 = fast_tanh(z2 + brv.z);
    h3 = fast_tanh(z3 + brv.w);
    pv = pvn;
  }
  if (sl == 0) *(float4*)&out[s * 4] = make_float4(h0, h1, h2, h3);
}

extern "C" void kernel_launch(void* const* d_in, const int* in_sizes, int n_in,
                              void* d_out, int out_size, void* d_ws, size_t ws_size,
                              hipStream_t stream) {
  const float* x      = (const float*)d_in[0];   // (512,128,512)
  const float* W_enc  = (const float*)d_in[1];   // (516,4)
  const float* b_enc  = (const float*)d_in[2];   // (4)
  const float* theta  = (const float*)d_in[3];   // (2,4,3)
  const float* W_read = (const float*)d_in[4];   // (4,4)
  const float* b_read = (const float*)d_in[5];   // (4)
  float* out = (float*)d_out;                    // (512,4)
  float* ws  = (float*)d_ws;

  hipLaunchKernelGGL(setup_kernel, dim3(1), dim3(64), 0, stream,
                     theta, W_read, b_read, W_enc, ws);
  hipLaunchKernelGGL(enc_gemm, dim3(512), dim3(256), 0, stream,
                     x, W_enc, b_enc, ws);
  hipLaunchKernelGGL(recur_kernel, dim3(128), dim3(64), 0, stream,
                     ws, out);
}

// Round 2
// 243.836 us; speedup vs baseline: 1.0806x; 1.0806x over previous
//
#include <hip/hip_runtime.h>

// ws layout (float offsets)
#define OFF_PRE 0   // 65536*4 floats: pre[t*512+b][q] = x[b,t,:]@W_enc[:512] + b_enc

// ---- DPP rotate-reduce within each 16-lane row (full sum lands in all lanes)
template<int CTRL>
__device__ __forceinline__ float dpp_movf(float x) {
  return __int_as_float(__builtin_amdgcn_update_dpp(
      0, __float_as_int(x), CTRL, 0xf, 0xf, true));
}
__device__ __forceinline__ float rowsum16(float x) {
  x += dpp_movf<0x128>(x);   // row_ror:8
  x += dpp_movf<0x124>(x);   // row_ror:4
  x += dpp_movf<0x122>(x);   // row_ror:2
  x += dpp_movf<0x121>(x);   // row_ror:1
  return x;
}

__device__ __forceinline__ float fast_tanh(float x) {
  // tanh(x) = 1 - 2/(exp(2x)+1); exp via v_exp_f32 (exp2), rcp via v_rcp_f32
  float e = __builtin_amdgcn_exp2f(x * 2.8853902f);          // 2*log2(e)
  return 1.0f - 2.0f * __builtin_amdgcn_rcpf(e + 1.0f);
}

// ---------------------------------------------------------------------------
// pre[t,b,:] = x[b,t,:] @ W_enc[:512,:] + b_enc      (memory-bound, 128 MB read)
// 16 lanes per row; lane j covers e = c*64 + j*4 + {0..3}, c = 0..7
// ---------------------------------------------------------------------------
__global__ __launch_bounds__(256, 2) void enc_gemm(const float* __restrict__ x,
                                                   const float* __restrict__ W_enc,
                                                   const float* __restrict__ b_enc,
                                                   float* __restrict__ ws) {
  const int j = threadIdx.x & 15;
  const int g = (blockIdx.x * 256 + threadIdx.x) >> 4;     // group id: 0..8191

  float4 W[8][4];
  #pragma unroll
  for (int c = 0; c < 8; ++c)
    #pragma unroll
    for (int k = 0; k < 4; ++k)
      W[c][k] = *(const float4*)&W_enc[(c * 64 + j * 4 + k) * 4];

  const float4 be = *(const float4*)b_enc;
  float* pre = ws + OFF_PRE;

  for (int r = g; r < 65536; r += 8192) {                  // row = b*128 + t
    const float* xr = x + (size_t)r * 512;
    float a0 = 0.f, a1 = 0.f, a2 = 0.f, a3 = 0.f;
    #pragma unroll
    for (int c = 0; c < 8; ++c) {
      float4 xv = *(const float4*)&xr[c * 64 + (j << 2)];
      a0 = fmaf(xv.x, W[c][0].x, a0); a0 = fmaf(xv.y, W[c][1].x, a0);
      a0 = fmaf(xv.z, W[c][2].x, a0); a0 = fmaf(xv.w, W[c][3].x, a0);
      a1 = fmaf(xv.x, W[c][0].y, a1); a1 = fmaf(xv.y, W[c][1].y, a1);
      a1 = fmaf(xv.z, W[c][2].y, a1); a1 = fmaf(xv.w, W[c][3].y, a1);
      a2 = fmaf(xv.x, W[c][0].z, a2); a2 = fmaf(xv.y, W[c][1].z, a2);
      a2 = fmaf(xv.z, W[c][2].z, a2); a2 = fmaf(xv.w, W[c][3].z, a2);
      a3 = fmaf(xv.x, W[c][0].w, a3); a3 = fmaf(xv.y, W[c][1].w, a3);
      a3 = fmaf(xv.z, W[c][2].w, a3); a3 = fmaf(xv.w, W[c][3].w, a3);
    }
    a0 = rowsum16(a0); a1 = rowsum16(a1); a2 = rowsum16(a2); a3 = rowsum16(a3);
    if (j == 0) {
      const int t = r & 127, b = r >> 7;
      *(float4*)&pre[(size_t)(t * 512 + b) * 4] =
          make_float4(a0 + be.x, a1 + be.y, a2 + be.z, a3 + be.w);
    }
  }
}

// ---------------------------------------------------------------------------
// Recurrence: 16 lanes per sample; lane = one statevector index.
// Prologue: each lane builds row sl of V in-register by simulating V^T e_sl
// (reversed circuit, transposed gates; CNOT is symmetric), plus its H row.
// Per step: ang = tanh(pre + h@W2); enc = product state; w = Vrow . enc;
// p = |w|^2; z_j = rowsum16(p*H[sl][j]) (DPP); h = tanh(z + br).
// ---------------------------------------------------------------------------
__global__ __launch_bounds__(64) void recur_kernel(const float* __restrict__ theta,
                                                   const float* __restrict__ W_read,
                                                   const float* __restrict__ b_read,
                                                   const float* __restrict__ W_enc,
                                                   const float* __restrict__ ws,
                                                   float* __restrict__ out) {
  const int gtid = blockIdx.x * 64 + threadIdx.x;
  const int s  = gtid >> 4;               // sample 0..511
  const int sl = threadIdx.x & 15;        // statevector index

  // ---- per-lane constants ----
  float W2[16];
  #pragma unroll
  for (int jj = 0; jj < 16; ++jj) W2[jj] = W_enc[2048 + jj];   // rows 512..515 of (516,4)
  const float br0 = b_read[0], br1 = b_read[1], br2 = b_read[2], br3 = b_read[3];

  float Hv0 = 0.f, Hv1 = 0.f, Hv2 = 0.f, Hv3 = 0.f;
  #pragma unroll
  for (int q = 0; q < 4; ++q) {
    float sgn = ((sl >> (3 - q)) & 1) ? -1.0f : 1.0f;   // wire q <-> bit (3-q)
    Hv0 += sgn * W_read[q * 4 + 0];
    Hv1 += sgn * W_read[q * 4 + 1];
    Hv2 += sgn * W_read[q * 4 + 2];
    Hv3 += sgn * W_read[q * 4 + 3];
  }

  // ---- V row sl: simulate V^T e_sl = reversed circuit with transposed gates ----
  float Vr[16], Vi[16];
  #pragma unroll
  for (int i = 0; i < 16; ++i) { Vr[i] = (i == sl) ? 1.f : 0.f; Vi[i] = 0.f; }

  #pragma unroll
  for (int l = 1; l >= 0; --l) {
    #pragma unroll
    for (int c = 2; c >= 0; --c) {                         // CNOT(c,c+1), reversed order
      const int mc = 8 >> c, mt = 8 >> (c + 1);
      #pragma unroll
      for (int i = 0; i < 16; ++i) {
        if ((i & mc) && !(i & mt)) {
          const int i1 = i | mt;
          float tr = Vr[i]; Vr[i] = Vr[i1]; Vr[i1] = tr;
          float ti = Vi[i]; Vi[i] = Vi[i1]; Vi[i1] = ti;
        }
      }
    }
    #pragma unroll
    for (int q = 0; q < 4; ++q) {                          // 1q gates commute; transposed
      const float a0 = 0.5f * theta[l * 12 + q * 3 + 0];   // RX angle/2
      const float a1 = 0.5f * theta[l * 12 + q * 3 + 1];   // RZ angle/2
      const float a2 = 0.5f * theta[l * 12 + q * 3 + 2];   // RY angle/2
      float cx = cosf(a0), sx = sinf(a0);
      float cz = cosf(a1), sz = sinf(a1);
      float cy = cosf(a2), sy = sinf(a2);
      // M = RZ @ RX
      float m00r =  cz * cx, m00i = -sz * cx;
      float m01r = -sz * sx, m01i = -cz * sx;
      float m10r =  sz * sx, m10i = -cz * sx;
      float m11r =  cz * cx, m11i =  sz * cx;
      // U = RY @ M   (RY real)
      float u00r = cy * m00r - sy * m10r, u00i = cy * m00i - sy * m10i;
      float u01r = cy * m01r - sy * m11r, u01i = cy * m01i - sy * m11i;
      float u10r = sy * m00r + cy * m10r, u10i = sy * m00i + cy * m10i;
      float u11r = sy * m01r + cy * m11r, u11i = sy * m01i + cy * m11i;
      const int m = 8 >> q;                                // wire q <-> bit (3-q)
      #pragma unroll
      for (int i = 0; i < 16; ++i) {
        if (i & m) continue;
        const int i1 = i | m;
        float ar = Vr[i], ai = Vi[i], brr = Vr[i1], bii = Vi[i1];
        // transposed 2x2: [[u00,u10],[u01,u11]]
        Vr[i]  = u00r * ar - u00i * ai + u10r * brr - u10i * bii;
        Vi[i]  = u00r * ai + u00i * ar + u10r * bii + u10i * brr;
        Vr[i1] = u01r * ar - u01i * ai + u11r * brr - u11i * bii;
        Vi[i1] = u01r * ai + u01i * ar + u11r * bii + u11i * brr;
      }
    }
  }

  // ---- recurrence ----
  const float4* pre4 = (const float4*)(ws + OFF_PRE);
  float h0 = 0.f, h1 = 0.f, h2 = 0.f, h3 = 0.f;
  float4 pv = pre4[s];                    // t = 0

  for (int t = 0; t < 128; ++t) {
    const int tn = (t + 1 < 128) ? t + 1 : 127;
    float4 pvn = pre4[tn * 512 + s];      // prefetch next step

    float u0 = pv.x + h0 * W2[0]  + h1 * W2[4]  + h2 * W2[8]  + h3 * W2[12];
    float u1 = pv.y + h0 * W2[1]  + h1 * W2[5]  + h2 * W2[9]  + h3 * W2[13];
    float u2 = pv.z + h0 * W2[2]  + h1 * W2[6]  + h2 * W2[10] + h3 * W2[14];
    float u3 = pv.w + h0 * W2[3]  + h1 * W2[7]  + h2 * W2[11] + h3 * W2[15];
    float t0 = fast_tanh(u0), t1 = fast_tanh(u1), t2 = fast_tanh(u2), t3 = fast_tanh(u3);
    // sin/cos(ang/2) = sin/cos(2*pi * tanh/4): HW sin/cos take revolutions
    float r0 = t0 * 0.25f, r1 = t1 * 0.25f, r2 = t2 * 0.25f, r3 = t3 * 0.25f;
    float c0 = __builtin_amdgcn_cosf(r0), s0 = __builtin_amdgcn_sinf(r0);
    float c1 = __builtin_amdgcn_cosf(r1), s1 = __builtin_amdgcn_sinf(r1);
    float c2 = __builtin_amdgcn_cosf(r2), s2 = __builtin_amdgcn_sinf(r2);
    float c3 = __builtin_amdgcn_cosf(r3), s3 = __builtin_amdgcn_sinf(r3);

    // product-state tree: enc[j], j = w0*8 + w1*4 + w2*2 + w3
    float e00 = c0 * c1, e01 = c0 * s1, e10 = s0 * c1, e11 = s0 * s1;
    float f0 = e00 * c2, f1 = e00 * s2, f2 = e01 * c2, f3 = e01 * s2;
    float f4 = e10 * c2, f5 = e10 * s2, f6 = e11 * c2, f7 = e11 * s2;
    float enc[16];
    enc[0]  = f0 * c3; enc[1]  = f0 * s3; enc[2]  = f1 * c3; enc[3]  = f1 * s3;
    enc[4]  = f2 * c3; enc[5]  = f2 * s3; enc[6]  = f3 * c3; enc[7]  = f3 * s3;
    enc[8]  = f4 * c3; enc[9]  = f4 * s3; enc[10] = f5 * c3; enc[11] = f5 * s3;
    enc[12] = f6 * c3; enc[13] = f6 * s3; enc[14] = f7 * c3; enc[15] = f7 * s3;

    // this lane's final amplitude: row sl of V times enc (enc real)
    float wrA = 0.f, wrB = 0.f, wiA = 0.f, wiB = 0.f;
    #pragma unroll
    for (int jj = 0; jj < 8; ++jj)  { wrA = fmaf(Vr[jj], enc[jj], wrA); wiA = fmaf(Vi[jj], enc[jj], wiA); }
    #pragma unroll
    for (int jj = 8; jj < 16; ++jj) { wrB = fmaf(Vr[jj], enc[jj], wrB); wiB = fmaf(Vi[jj], enc[jj], wiB); }
    float wr = wrA + wrB, wi = wiA + wiB;
    float p  = wr * wr + wi * wi;

    // z_j = sum over the 16 lanes of p * H[sl][j]  (DPP rotate-reduce, ~VALU cost)
    float z0 = rowsum16(p * Hv0);
    float z1 = rowsum16(p * Hv1);
    float z2 = rowsum16(p * Hv2);
    float z3 = rowsum16(p * Hv3);

    h0 = fast_tanh(z0 + br0);
    h1 = fast_tanh(z1 + br1);
    h2 = fast_tanh(z2 + br2);
    h3 = fast_tanh(z3 + br3);
    pv = pvn;
  }
  if (sl == 0) *(float4*)&out[s * 4] = make_float4(h0, h1, h2, h3);
}

extern "C" void kernel_launch(void* const* d_in, const int* in_sizes, int n_in,
                              void* d_out, int out_size, void* d_ws, size_t ws_size,
                              hipStream_t stream) {
  const float* x      = (const float*)d_in[0];   // (512,128,512)
  const float* W_enc  = (const float*)d_in[1];   // (516,4)
  const float* b_enc  = (const float*)d_in[2];   // (4)
  const float* theta  = (const float*)d_in[3];   // (2,4,3)
  const float* W_read = (const float*)d_in[4];   // (4,4)
  const float* b_read = (const float*)d_in[5];   // (4)
  float* out = (float*)d_out;                    // (512,4)
  float* ws  = (float*)d_ws;

  hipLaunchKernelGGL(enc_gemm, dim3(512), dim3(256), 0, stream,
                     x, W_enc, b_enc, ws);
  hipLaunchKernelGGL(recur_kernel, dim3(128), dim3(64), 0, stream,
                     theta, W_read, b_read, W_enc, ws, out);
}